// Round 4
// baseline (1117.399 us; speedup 1.0000x reference)
//
#include <hip/hip_runtime.h>
#include <math.h>

typedef __bf16 bf16;
typedef __bf16 bf16x8 __attribute__((ext_vector_type(8)));
typedef __bf16 bf16x4 __attribute__((ext_vector_type(4)));
typedef float  f32x4  __attribute__((ext_vector_type(4)));

// Problem constants
#define D_   768
#define E_   1536
#define S_   128
#define TT_  32768     // B*G*N tokens
#define B_   8

// ---------------- workspace layout (bytes) ----------------
// NOTE r4 fix: mask is 8*16*16 f32 = 8192 B (was given 4096 -> spilled into XN,
// corrupting mask for b>=4 => the x8.7 error). mask + invf now at tail.
#define OFF_W1T   0UL                       // 3200x768 bf16  = 4,915,200
#define OFF_W2T   4915200UL                 // 768x1536 bf16  = 2,359,296
#define OFF_TAB   7274496UL                 // 4096x64 float2 = 2,097,152
#define OFF_XN    9375744UL                 // 32768x768 bf16 = 50,331,648
#define OFF_KER   OFF_XN                    //   reuse: 128x256x256 bf16 = 16,777,216
#define OFF_QQ    (OFF_XN + 16777216UL)     //   reuse: 32768x128 bf16  =  8,388,608
#define OFF_QK    (OFF_XN + 25165824UL)     //   reuse: 8,388,608
#define OFF_LQ    (OFF_XN + 33554432UL)     //   reuse: 8,388,608 (ends XN+41.9M < 50.3M)
#define OFF_U     59707392UL                // 32768x1536 bf16 = 100,663,296 (combine in-place -> P)
#define OFF_Z     160370688UL               // 32768x128 bf16 ; reuse: P2 f32 (same 8,388,608 bytes)
#define OFF_LK    168759296UL               // 8,388,608 ; reuse: T1
#define OFF_LQT   177147904UL               // 8,388,608 ; reuse: amix (4,194,304) + kvT (3,145,728)
#define OFF_LKT   185536512UL               // 8,388,608
#define OFF_MASK  193925120UL               // 8x16x16 f32 = 8,192  (FULL size now)
#define OFF_INVF  193933312UL               // 64 f32 = 256 -> end 193,933,568 (~185 MiB)

// ---------------- generic MFMA GEMM: C[M,N] = A[M,K] * B[N,K]^T ----------------
#define BM 128
#define BN 128
#define BK 32
#define LSTR 40   // BK + 8 pad

template <class Epi, bool DUAL>
__global__ __launch_bounds__(256) void gemm_bt(
    const bf16* __restrict__ A, const bf16* __restrict__ B,
    int lda, int ldb, int K,
    long sAb, long sAg, long sBb, long sBg,
    const bf16* __restrict__ A2, const bf16* __restrict__ B2,
    int lda2, int ldb2, int K2,
    long sA2b, long sA2g, long sB2b, long sB2g,
    int gdiv, Epi epi)
{
  __shared__ bf16 As[BM * LSTR];
  __shared__ bf16 Bs[BN * LSTR];
  const int z = blockIdx.z;
  const int bb = z / gdiv, gg = z % gdiv;
  const int tid  = threadIdx.x;
  const int lane = tid & 63, wave = tid >> 6;
  const int wm = (wave >> 1) * 64, wn = (wave & 1) * 64;
  const int lrow = lane & 15, quad = lane >> 4;
  const int srow = tid >> 2, scol = (tid & 3) * 8;

  f32x4 acc[4][4] = {};

  auto kloop = [&](const bf16* __restrict__ Ab, const bf16* __restrict__ Bb,
                   int lda_, int ldb_, int K_) {
    for (int k0 = 0; k0 < K_; k0 += BK) {
      __syncthreads();
      *(int4*)&As[srow * LSTR + scol]        = *(const int4*)&Ab[(long)srow * lda_ + k0 + scol];
      *(int4*)&As[(srow + 64) * LSTR + scol] = *(const int4*)&Ab[(long)(srow + 64) * lda_ + k0 + scol];
      *(int4*)&Bs[srow * LSTR + scol]        = *(const int4*)&Bb[(long)srow * ldb_ + k0 + scol];
      *(int4*)&Bs[(srow + 64) * LSTR + scol] = *(const int4*)&Bb[(long)(srow + 64) * ldb_ + k0 + scol];
      __syncthreads();
      bf16x8 af[4], bfr[4];
#pragma unroll
      for (int i = 0; i < 4; i++) af[i]  = *(const bf16x8*)&As[(wm + i * 16 + lrow) * LSTR + quad * 8];
#pragma unroll
      for (int i = 0; i < 4; i++) bfr[i] = *(const bf16x8*)&Bs[(wn + i * 16 + lrow) * LSTR + quad * 8];
#pragma unroll
      for (int mi = 0; mi < 4; mi++)
#pragma unroll
        for (int ni = 0; ni < 4; ni++)
          acc[mi][ni] = __builtin_amdgcn_mfma_f32_16x16x32_bf16(af[mi], bfr[ni], acc[mi][ni], 0, 0, 0);
    }
  };

  kloop(A + (long)bb * sAb + (long)gg * sAg + (long)blockIdx.x * BM * lda,
        B + (long)bb * sBb + (long)gg * sBg + (long)blockIdx.y * BN * ldb, lda, ldb, K);
  if constexpr (DUAL)
    kloop(A2 + (long)bb * sA2b + (long)gg * sA2g + (long)blockIdx.x * BM * lda2,
          B2 + (long)bb * sB2b + (long)gg * sB2g + (long)blockIdx.y * BN * ldb2, lda2, ldb2, K2);

  // C/D layout: col = lane&15, row = quad*4 + j  [verified m89/m91]
  const int rowbase = blockIdx.x * BM + wm + quad * 4;
  const int colbase = blockIdx.y * BN + wn + lrow;
#pragma unroll
  for (int mi = 0; mi < 4; mi++)
#pragma unroll
    for (int ni = 0; ni < 4; ni++)
      epi(rowbase + mi * 16, colbase + ni * 16, bb, gg, acc[mi][ni]);
}

// ---------------- epilogues (a[j] belongs to row row0+j, fixed col) ----------------
struct EpiGemm1 {   // silu(x@W1 + b1) -> u, v (direct into vT layout), z
  const float* b1; bf16* u; bf16* vT; bf16* z;
  __device__ void operator()(int row0, int col, int, int, f32x4 a) const {
    float s[4];
    const float bias = b1[col];
#pragma unroll
    for (int j = 0; j < 4; j++) { float x = a[j] + bias; s[j] = x / (1.f + expf(-x)); }
    if (col < E_) {
#pragma unroll
      for (int j = 0; j < 4; j++) u[(long)(row0 + j) * E_ + col] = (bf16)s[j];
    } else if (col < 2 * E_) {
      const int e = col - E_, b = row0 >> 12, t = row0 & 4095;
      bf16x4 o;
#pragma unroll
      for (int j = 0; j < 4; j++) o[j] = (bf16)s[j];
      *(bf16x4*)&vT[((long)(b * E_ + e)) * 4096 + t] = o;
    } else {
      const int sc = col - 2 * E_;
#pragma unroll
      for (int j = 0; j < 4; j++) z[(long)(row0 + j) * S_ + sc] = (bf16)s[j];
    }
  }
};
struct EpiF32 {
  float* C; long sCb, sCg; int ldc;
  __device__ void operator()(int row0, int col, int bb, int gg, f32x4 a) const {
#pragma unroll
    for (int j = 0; j < 4; j++)
      C[(long)bb * sCb + (long)gg * sCg + (long)(row0 + j) * ldc + col] = a[j];
  }
};
struct EpiBf16 {
  bf16* C; long sCb, sCg; int ldc;
  __device__ void operator()(int row0, int col, int bb, int gg, f32x4 a) const {
#pragma unroll
    for (int j = 0; j < 4; j++)
      C[(long)bb * sCb + (long)gg * sCg + (long)(row0 + j) * ldc + col] = (bf16)a[j];
  }
};
struct EpiKer {   // relu(qk/n + w_rel[511+col-row])^2
  bf16* C; const float* wrel;
  __device__ void operator()(int row0, int col, int bb, int, f32x4 a) const {
#pragma unroll
    for (int j = 0; j < 4; j++) {
      float v = a[j] * (1.f / 256.f) + wrel[511 + col - (row0 + j)];
      v = fmaxf(v, 0.f);
      C[(long)bb * 65536 + (long)(row0 + j) * 256 + col] = (bf16)(v * v);
    }
  }
};
struct EpiCombine {   // P = u * (quadratic + linear), in-place over u
  bf16* u;
  __device__ void operator()(int row0, int col, int bb, int gg, f32x4 a) const {
#pragma unroll
    for (int j = 0; j < 4; j++) {
      long idx = ((long)((bb * 16 + gg) * 256 + row0 + j)) * E_ + col;
      u[idx] = (bf16)((float)u[idx] * a[j]);
    }
  }
};
struct EpiFinal {   // out = P@W2 + b2 + shortcut
  float* out; const float* b2; const float* x0;
  __device__ void operator()(int row0, int col, int, int, f32x4 a) const {
#pragma unroll
    for (int j = 0; j < 4; j++) {
      long idx = (long)(row0 + j) * D_ + col;
      out[idx] = a[j] + b2[col] + x0[idx];
    }
  }
};

// ---------------- LayerNorm -> bf16 ----------------
__global__ __launch_bounds__(256) void ln_kernel(
    const float* __restrict__ x, const float* __restrict__ w,
    const float* __restrict__ b, bf16* __restrict__ xn)
{
  const long t = blockIdx.x;
  const float* row = x + t * D_;
  const int tid = threadIdx.x;
  float v0 = row[tid], v1 = row[tid + 256], v2 = row[tid + 512];
  float s = v0 + v1 + v2;
  float sq = v0 * v0 + v1 * v1 + v2 * v2;
#pragma unroll
  for (int off = 32; off; off >>= 1) {
    s  += __shfl_down(s, off, 64);
    sq += __shfl_down(sq, off, 64);
  }
  __shared__ float red[2][4];
  const int wave = tid >> 6, lane = tid & 63;
  if (lane == 0) { red[0][wave] = s; red[1][wave] = sq; }
  __syncthreads();
  s  = red[0][0] + red[0][1] + red[0][2] + red[0][3];
  sq = red[1][0] + red[1][1] + red[1][2] + red[1][3];
  const float mean = s * (1.f / 768.f);
  const float var  = sq * (1.f / 768.f) - mean * mean;
  const float rs   = rsqrtf(var + 1e-5f);
  xn[t * D_ + tid]       = (bf16)((v0 - mean) * rs * w[tid] + b[tid]);
  xn[t * D_ + tid + 256] = (bf16)((v1 - mean) * rs * w[tid + 256] + b[tid + 256]);
  xn[t * D_ + tid + 512] = (bf16)((v2 - mean) * rs * w[tid + 512] + b[tid + 512]);
}

// ---------------- tiled transpose + cast to bf16 ----------------
template <class TI>
__global__ __launch_bounds__(256) void transpose_cast(
    const TI* __restrict__ in, bf16* __restrict__ out,
    int R, int C, long sInB, long sOutB)
{
  __shared__ float tile[64][65];
  const TI* ib = in  + (long)blockIdx.z * sInB;
  bf16*     ob = out + (long)blockIdx.z * sOutB;
  const int c0 = blockIdx.x * 64, r0 = blockIdx.y * 64;
  const int lc = threadIdx.x & 63, lr0 = threadIdx.x >> 6;
#pragma unroll
  for (int i = 0; i < 16; i++) {
    int r = lr0 + i * 4;
    tile[r][lc] = (float)ib[(long)(r0 + r) * C + c0 + lc];
  }
  __syncthreads();
#pragma unroll
  for (int i = 0; i < 16; i++) {
    int r = lr0 + i * 4;
    ob[(long)(c0 + r) * R + r0 + lc] = (bf16)tile[lc][r];
  }
}

// ---------------- RoPE sin/cos table ----------------
// invf[64] computed on HOST with powf (same glibc numpy's npy_powf uses) and
// uploaded; arg = f32(p)*invf (bit-exact vs np); sin/cos in f64 of that f32
// arg => matches numpy's f32-accurate trig within ~2 ulp.
__global__ __launch_bounds__(256) void rope_table_kernel(
    const float* __restrict__ invf, float2* __restrict__ tab)
{
  int idx = blockIdx.x * 256 + threadIdx.x;   // 4096*64 entries
  int p = idx >> 6, i = idx & 63;
  float arg = (float)p * invf[i];
  double a = (double)arg;
  tab[idx] = make_float2((float)sin(a), (float)cos(a));
}

// ---------------- z -> gamma/beta -> rope -> 4 gate rows ----------------
__global__ __launch_bounds__(128) void rope_kernel(
    const bf16* __restrict__ zbuf, const float* __restrict__ gamma,
    const float* __restrict__ beta, const float2* __restrict__ tab,
    bf16* __restrict__ qq, bf16* __restrict__ qk,
    bf16* __restrict__ lq, bf16* __restrict__ lk)
{
  const long t = blockIdx.x;
  const int s = threadIdx.x;
  const int p = (int)(t & 4095);
  const int i = s & 63;
  const float2 sc = tab[p * 64 + i];
  const bf16* zr = zbuf + t * S_;
  const float zlo = (float)zr[i], zhi = (float)zr[i + 64];
  bf16* outs[4] = {qq, qk, lq, lk};
#pragma unroll
  for (int r = 0; r < 4; r++) {
    float zl = zlo * gamma[r * 128 + i]      + beta[r * 128 + i];
    float zh = zhi * gamma[r * 128 + i + 64] + beta[r * 128 + i + 64];
    float val = (s < 64) ? (zl * sc.y - zh * sc.x) : (zh * sc.y + zl * sc.x);
    outs[r][t * S_ + s] = (bf16)val;
  }
}

// ---------------- segment mask (boring serial version) ----------------
__global__ __launch_bounds__(64) void mask_kernel(const int* __restrict__ seg, float* __restrict__ mask) {
  __shared__ int mn[16], mx[16];
  const int b = blockIdx.x, tid = threadIdx.x;
  if (tid < 16) {
    const int* p = seg + (long)b * 4096 + tid * 256;
    int lo = p[0], hi = p[0];
    for (int i = 1; i < 256; i++) { int v = p[i]; lo = min(lo, v); hi = max(hi, v); }
    mn[tid] = lo; mx[tid] = hi;
  }
  __syncthreads();
  if (tid < 16) {
    const int g = tid;
    float row[16]; float s = 0.f;
    for (int h = 0; h < 16; h++) {
      float o = (mn[g] <= mx[h] && mx[g] >= mn[h]) ? 1.f : 0.f;
      row[h] = o; s += o;
    }
    const float inv = 1.f / s;
    for (int h = 0; h < 16; h++) mask[((long)b * 16 + g) * 16 + h] = row[h] * inv;
  }
}

// ---------------- mask-mix of P2 (folds 1/n): amix[b,g] = sum_h mask[b,g,h]/n * P2[b,h] ----------------
__global__ __launch_bounds__(256) void mix_kernel(
    const float* __restrict__ P2, const float* __restrict__ mask, bf16* __restrict__ amix)
{
  const int z = blockIdx.x;          // b*16 + g
  const int b = z >> 4;
  float m[16];
#pragma unroll
  for (int h = 0; h < 16; h++) m[h] = mask[(long)z * 16 + h] * (1.f / 256.f);
  const float* Pb = P2 + (long)b * 16 * 16384;
  bf16* Ab = amix + (long)z * 16384;
#pragma unroll 4
  for (int j = 0; j < 16; j++) {
    int c = j * 256 + threadIdx.x;   // float4 chunk id (4096 per matrix)
    float ax = 0, ay = 0, az = 0, aw = 0;
#pragma unroll
    for (int h = 0; h < 16; h++) {
      float4 p = ((const float4*)(Pb + (long)h * 16384))[c];
      ax += m[h] * p.x; ay += m[h] * p.y; az += m[h] * p.z; aw += m[h] * p.w;
    }
    bf16x4 o; o[0] = (bf16)ax; o[1] = (bf16)ay; o[2] = (bf16)az; o[3] = (bf16)aw;
    *(bf16x4*)&Ab[(long)c * 4] = o;
  }
}

// ---------------- launch ----------------
extern "C" void kernel_launch(void* const* d_in, const int* in_sizes, int n_in,
                              void* d_out, int out_size, void* d_ws, size_t ws_size,
                              hipStream_t stream)
{
  const float* x0    = (const float*)d_in[0];
  const int*   seg   = (const int*)d_in[1];
  const float* lnw   = (const float*)d_in[2];
  const float* lnb   = (const float*)d_in[3];
  const float* W1    = (const float*)d_in[4];
  const float* b1    = (const float*)d_in[5];
  const float* gamma = (const float*)d_in[6];
  const float* beta  = (const float*)d_in[7];
  const float* W2    = (const float*)d_in[8];
  const float* b2    = (const float*)d_in[9];
  const float* wrel  = (const float*)d_in[10];
  float* out = (float*)d_out;
  char* ws = (char*)d_ws;

  bf16*   w1t   = (bf16*)(ws + OFF_W1T);
  bf16*   w2t   = (bf16*)(ws + OFF_W2T);
  float2* tab   = (float2*)(ws + OFF_TAB);
  bf16*   xn    = (bf16*)(ws + OFF_XN);
  bf16*   ker   = (bf16*)(ws + OFF_KER);
  bf16*   qq    = (bf16*)(ws + OFF_QQ);
  bf16*   qk    = (bf16*)(ws + OFF_QK);
  bf16*   lq    = (bf16*)(ws + OFF_LQ);
  bf16*   u     = (bf16*)(ws + OFF_U);
  bf16*   zb    = (bf16*)(ws + OFF_Z);
  float*  P2    = (float*)(ws + OFF_Z);       // reuse (z dead after rope)
  bf16*   lk    = (bf16*)(ws + OFF_LK);
  bf16*   T1    = (bf16*)(ws + OFF_LK);       // reuse (lk dead after lkT)
  bf16*   lqT   = (bf16*)(ws + OFF_LQT);
  bf16*   amix  = (bf16*)(ws + OFF_LQT);      // reuse (lqT dead after P2)
  bf16*   kvT   = (bf16*)(ws + OFF_LQT + 4194304UL);
  bf16*   lkT   = (bf16*)(ws + OFF_LKT);
  float*  maskb = (float*)(ws + OFF_MASK);
  float*  invfd = (float*)(ws + OFF_INVF);
  bf16*   vTd   = (bf16*)d_out;               // vT lives in d_out (exact fit), dead before final GEMM

  // invf on host with the same libm numpy uses (recomputed every call; static storage only)
  static float h_invf[64];
  for (int i = 0; i < 64; i++) h_invf[i] = powf(10000.0f, (float)i * (1.0f / 64.0f));
  hipMemcpyAsync(invfd, h_invf, 64 * sizeof(float), hipMemcpyHostToDevice, stream);

  // prep (independent)
  transpose_cast<float><<<dim3(50, 12, 1), 256, 0, stream>>>(W1, w1t, 768, 3200, 0, 0);
  transpose_cast<float><<<dim3(12, 24, 1), 256, 0, stream>>>(W2, w2t, 1536, 768, 0, 0);
  rope_table_kernel<<<1024, 256, 0, stream>>>(invfd, tab);
  mask_kernel<<<8, 64, 0, stream>>>(seg, maskb);

  // LN -> xn (bf16)
  ln_kernel<<<TT_, 256, 0, stream>>>(x0, lnw, lnb, xn);

  // GEMM1: silu(xn@W1 + b1) -> u, vT(d_out), z
  gemm_bt<EpiGemm1, false><<<dim3(256, 25, 1), 256, 0, stream>>>(
      xn, w1t, 768, 768, 768, 0, 0, 0, 0,
      nullptr, nullptr, 0, 0, 0, 0, 0, 0, 0, 1, EpiGemm1{b1, u, vTd, zb});

  // z -> 4 rope'd gate rows
  rope_kernel<<<TT_, 128, 0, stream>>>(zb, gamma, beta, tab, qq, qk, lq, lk);

  // lq/lk -> transposed (per b: 4096x128 -> 128x4096)
  transpose_cast<bf16><<<dim3(2, 64, 8), 256, 0, stream>>>(lq, lqT, 4096, 128, 524288, 524288);
  transpose_cast<bf16><<<dim3(2, 64, 8), 256, 0, stream>>>(lk, lkT, 4096, 128, 524288, 524288);

  // P2[b,h][s][k] = sum_c lq[c][s] lk[c][k]  (into dead z region)
  gemm_bt<EpiF32, false><<<dim3(1, 1, 128), 256, 0, stream>>>(
      lqT, lkT, 4096, 4096, 256, 524288, 256, 524288, 256,
      nullptr, nullptr, 0, 0, 0, 0, 0, 0, 0, 16, EpiF32{P2, 262144, 16384, 128});

  // amix[b,g] = sum_h mask/n * P2[b,h]  (into dead lqT region)
  mix_kernel<<<128, 256, 0, stream>>>(P2, maskb, amix);

  // kvT[b][e][s] = sum_t v[t][e] lk[t][s]
  gemm_bt<EpiBf16, false><<<dim3(12, 1, 8), 256, 0, stream>>>(
      vTd, lkT, 4096, 4096, 4096, 6291456, 0, 524288, 0,
      nullptr, nullptr, 0, 0, 0, 0, 0, 0, 0, 1, EpiBf16{kvT, 196608, 0, 128});

  // T1[t][s] = sum_k lq[t][k] amix[b,g][s][k]  (into dead lk region)
  gemm_bt<EpiBf16, false><<<dim3(2, 1, 128), 256, 0, stream>>>(
      lq, amix, 128, 128, 128, 32768, 0, 16384, 0,
      nullptr, nullptr, 0, 0, 0, 0, 0, 0, 0, 1, EpiBf16{T1, 32768, 0, 128});

  // ker[b,g][n][m] = relu(qq.qk/n + bias)^2  (into dead xn region)
  gemm_bt<EpiKer, false><<<dim3(2, 2, 128), 256, 0, stream>>>(
      qq, qk, 128, 128, 128, 32768, 0, 32768, 0,
      nullptr, nullptr, 0, 0, 0, 0, 0, 0, 0, 1, EpiKer{ker, wrel});

  // combine (dual-K): P = u * (ker@v + T1@kv), in-place over u
  gemm_bt<EpiCombine, true><<<dim3(2, 12, 128), 256, 0, stream>>>(
      ker, vTd, 256, 4096, 256, 1048576, 65536, 6291456, 256,
      T1, kvT, 128, 128, 128, 524288, 32768, 196608, 0, 16, EpiCombine{u});

  // out = P@W2 + b2 + shortcut (vT in d_out is dead now)
  gemm_bt<EpiFinal, false><<<dim3(256, 6, 1), 256, 0, stream>>>(
      u, w2t, 1536, 1536, 1536, 0, 0, 0, 0,
      nullptr, nullptr, 0, 0, 0, 0, 0, 0, 0, 1, EpiFinal{out, b2, x0});
}

// Round 5
// 1103.584 us; speedup vs baseline: 1.0125x; 1.0125x over previous
//
#include <hip/hip_runtime.h>
#include <math.h>

typedef __bf16 bf16;
typedef __bf16 bf16x8 __attribute__((ext_vector_type(8)));
typedef __bf16 bf16x4 __attribute__((ext_vector_type(4)));
typedef float  f32x4  __attribute__((ext_vector_type(4)));

// Problem constants
#define D_   768
#define E_   1536
#define S_   128
#define TT_  32768     // B*G*N tokens
#define B_   8

// ---------------- workspace layout (bytes) ----------------
#define OFF_W1T   0UL                       // 3200x768 bf16  = 4,915,200
#define OFF_W2T   4915200UL                 // 768x1536 bf16  = 2,359,296
#define OFF_TAB   7274496UL                 // 4096x64 float2 = 2,097,152
#define OFF_XN    9375744UL                 // 32768x768 bf16 = 50,331,648
#define OFF_KER   OFF_XN                    //   reuse: 128x256x256 bf16 = 16,777,216
#define OFF_QQ    (OFF_XN + 16777216UL)     //   reuse: 32768x128 bf16  =  8,388,608
#define OFF_QK    (OFF_XN + 25165824UL)     //   reuse: 8,388,608
#define OFF_LQ    (OFF_XN + 33554432UL)     //   reuse: 8,388,608 (ends XN+41.9M < 50.3M)
#define OFF_U     59707392UL                // 32768x1536 bf16 = 100,663,296 (combine in-place -> P)
#define OFF_Z     160370688UL               // 32768x128 bf16 ; reuse: P2 f32 (same 8,388,608 bytes)
#define OFF_LK    168759296UL               // 8,388,608 ; reuse: T1
#define OFF_LQT   177147904UL               // 8,388,608 ; reuse: amix (4,194,304) + kvT (3,145,728)
#define OFF_LKT   185536512UL               // 8,388,608
#define OFF_MASK  193925120UL               // 8x16x16 f32 = 8,192 (FULL size)
#define OFF_INVF  193933312UL               // 64 f32 -> end 193,933,568 (~185 MiB)

// ---------------- async global->LDS staging (m97 structure) ----------------
// HW semantics: per-lane global gather, LDS dest = wave-uniform base + lane*16
// [measured: learn_hip m97/m104/m108]. So LDS tiles are UNPADDED (64 B rows),
// and lane L of a wave sources row (L>>2), col-chunk (L&3) of its 16-row slab.
__device__ __forceinline__ void gl_lds16(const bf16* g, bf16* l) {
  __builtin_amdgcn_global_load_lds(
      (const __attribute__((address_space(1))) unsigned int*)g,
      (__attribute__((address_space(3))) unsigned int*)l, 16, 0, 0);
}

// ---------------- generic MFMA GEMM: C[M,N] = A[M,K] * B[N,K]^T ----------------
#define BM 128
#define BN 128
#define BK 32

template <class Epi, bool DUAL>
__global__ __launch_bounds__(256) void gemm_bt(
    const bf16* __restrict__ A, const bf16* __restrict__ B,
    int lda, int ldb, int K,
    long sAb, long sAg, long sBb, long sBg,
    const bf16* __restrict__ A2, const bf16* __restrict__ B2,
    int lda2, int ldb2, int K2,
    long sA2b, long sA2g, long sB2b, long sB2g,
    int gdiv, Epi epi)
{
  __shared__ bf16 As[BM * BK];   // 8 KB, rows of 64 B, unpadded (global_load_lds layout)
  __shared__ bf16 Bs[BN * BK];
  const int z = blockIdx.z;
  const int bb = z / gdiv, gg = z % gdiv;
  const int tid  = threadIdx.x;
  const int lane = tid & 63, wave = tid >> 6;
  const int wm = (wave >> 1) * 64, wn = (wave & 1) * 64;
  const int lrow = lane & 15, quad = lane >> 4;
  // staging: wave w covers rows [w*16, w*16+16) and [w*16+64, w*16+80)
  const int srow = wave * 16 + (lane >> 2);
  const int scol = (lane & 3) * 8;
  bf16* ldsA0 = As + wave * 512;            // 16 rows * 32 elem
  bf16* ldsA1 = As + (wave + 4) * 512;
  bf16* ldsB0 = Bs + wave * 512;
  bf16* ldsB1 = Bs + (wave + 4) * 512;

  f32x4 acc[4][4] = {};

  auto kloop = [&](const bf16* __restrict__ Ab, const bf16* __restrict__ Bb,
                   int lda_, int ldb_, int K_) {
    for (int k0 = 0; k0 < K_; k0 += BK) {
      __syncthreads();   // previous tile's ds_reads done before overwrite
      gl_lds16(Ab + (long)srow * lda_ + k0 + scol,        ldsA0);
      gl_lds16(Ab + (long)(srow + 64) * lda_ + k0 + scol, ldsA1);
      gl_lds16(Bb + (long)srow * ldb_ + k0 + scol,        ldsB0);
      gl_lds16(Bb + (long)(srow + 64) * ldb_ + k0 + scol, ldsB1);
      __syncthreads();   // compiler drains vmcnt(0) before s_barrier => LDS writes visible
      bf16x8 af[4], bfr[4];
#pragma unroll
      for (int i = 0; i < 4; i++) af[i]  = *(const bf16x8*)&As[(wm + i * 16 + lrow) * BK + quad * 8];
#pragma unroll
      for (int i = 0; i < 4; i++) bfr[i] = *(const bf16x8*)&Bs[(wn + i * 16 + lrow) * BK + quad * 8];
#pragma unroll
      for (int mi = 0; mi < 4; mi++)
#pragma unroll
        for (int ni = 0; ni < 4; ni++)
          acc[mi][ni] = __builtin_amdgcn_mfma_f32_16x16x32_bf16(af[mi], bfr[ni], acc[mi][ni], 0, 0, 0);
    }
  };

  kloop(A + (long)bb * sAb + (long)gg * sAg + (long)blockIdx.x * BM * lda,
        B + (long)bb * sBb + (long)gg * sBg + (long)blockIdx.y * BN * ldb, lda, ldb, K);
  if constexpr (DUAL)
    kloop(A2 + (long)bb * sA2b + (long)gg * sA2g + (long)blockIdx.x * BM * lda2,
          B2 + (long)bb * sB2b + (long)gg * sB2g + (long)blockIdx.y * BN * ldb2, lda2, ldb2, K2);

  // C/D layout: col = lane&15, row = quad*4 + j  [verified m89/m91]
  const int rowbase = blockIdx.x * BM + wm + quad * 4;
  const int colbase = blockIdx.y * BN + wn + lrow;
#pragma unroll
  for (int mi = 0; mi < 4; mi++)
#pragma unroll
    for (int ni = 0; ni < 4; ni++)
      epi(rowbase + mi * 16, colbase + ni * 16, bb, gg, acc[mi][ni]);
}

// ---------------- epilogues (a[j] belongs to row row0+j, fixed col) ----------------
struct EpiGemm1 {   // silu(x@W1 + b1) -> u, v (direct into vT layout), z
  const float* b1; bf16* u; bf16* vT; bf16* z;
  __device__ void operator()(int row0, int col, int, int, f32x4 a) const {
    float s[4];
    const float bias = b1[col];
#pragma unroll
    for (int j = 0; j < 4; j++) { float x = a[j] + bias; s[j] = x / (1.f + expf(-x)); }
    if (col < E_) {
#pragma unroll
      for (int j = 0; j < 4; j++) u[(long)(row0 + j) * E_ + col] = (bf16)s[j];
    } else if (col < 2 * E_) {
      const int e = col - E_, b = row0 >> 12, t = row0 & 4095;
      bf16x4 o;
#pragma unroll
      for (int j = 0; j < 4; j++) o[j] = (bf16)s[j];
      *(bf16x4*)&vT[((long)(b * E_ + e)) * 4096 + t] = o;
    } else {
      const int sc = col - 2 * E_;
#pragma unroll
      for (int j = 0; j < 4; j++) z[(long)(row0 + j) * S_ + sc] = (bf16)s[j];
    }
  }
};
struct EpiF32 {
  float* C; long sCb, sCg; int ldc;
  __device__ void operator()(int row0, int col, int bb, int gg, f32x4 a) const {
#pragma unroll
    for (int j = 0; j < 4; j++)
      C[(long)bb * sCb + (long)gg * sCg + (long)(row0 + j) * ldc + col] = a[j];
  }
};
struct EpiBf16 {
  bf16* C; long sCb, sCg; int ldc;
  __device__ void operator()(int row0, int col, int bb, int gg, f32x4 a) const {
#pragma unroll
    for (int j = 0; j < 4; j++)
      C[(long)bb * sCb + (long)gg * sCg + (long)(row0 + j) * ldc + col] = (bf16)a[j];
  }
};
struct EpiKer {   // relu(qk/n + w_rel[511+col-row])^2
  bf16* C; const float* wrel;
  __device__ void operator()(int row0, int col, int bb, int, f32x4 a) const {
#pragma unroll
    for (int j = 0; j < 4; j++) {
      float v = a[j] * (1.f / 256.f) + wrel[511 + col - (row0 + j)];
      v = fmaxf(v, 0.f);
      C[(long)bb * 65536 + (long)(row0 + j) * 256 + col] = (bf16)(v * v);
    }
  }
};
struct EpiCombine {   // P = u * (quadratic + linear), in-place over u
  bf16* u;
  __device__ void operator()(int row0, int col, int bb, int gg, f32x4 a) const {
#pragma unroll
    for (int j = 0; j < 4; j++) {
      long idx = ((long)((bb * 16 + gg) * 256 + row0 + j)) * E_ + col;
      u[idx] = (bf16)((float)u[idx] * a[j]);
    }
  }
};
struct EpiFinal {   // out = P@W2 + b2 + shortcut
  float* out; const float* b2; const float* x0;
  __device__ void operator()(int row0, int col, int, int, f32x4 a) const {
#pragma unroll
    for (int j = 0; j < 4; j++) {
      long idx = (long)(row0 + j) * D_ + col;
      out[idx] = a[j] + b2[col] + x0[idx];
    }
  }
};

// ---------------- LayerNorm -> bf16 ----------------
__global__ __launch_bounds__(256) void ln_kernel(
    const float* __restrict__ x, const float* __restrict__ w,
    const float* __restrict__ b, bf16* __restrict__ xn)
{
  const long t = blockIdx.x;
  const float* row = x + t * D_;
  const int tid = threadIdx.x;
  float v0 = row[tid], v1 = row[tid + 256], v2 = row[tid + 512];
  float s = v0 + v1 + v2;
  float sq = v0 * v0 + v1 * v1 + v2 * v2;
#pragma unroll
  for (int off = 32; off; off >>= 1) {
    s  += __shfl_down(s, off, 64);
    sq += __shfl_down(sq, off, 64);
  }
  __shared__ float red[2][4];
  const int wave = tid >> 6, lane = tid & 63;
  if (lane == 0) { red[0][wave] = s; red[1][wave] = sq; }
  __syncthreads();
  s  = red[0][0] + red[0][1] + red[0][2] + red[0][3];
  sq = red[1][0] + red[1][1] + red[1][2] + red[1][3];
  const float mean = s * (1.f / 768.f);
  const float var  = sq * (1.f / 768.f) - mean * mean;
  const float rs   = rsqrtf(var + 1e-5f);
  xn[t * D_ + tid]       = (bf16)((v0 - mean) * rs * w[tid] + b[tid]);
  xn[t * D_ + tid + 256] = (bf16)((v1 - mean) * rs * w[tid + 256] + b[tid + 256]);
  xn[t * D_ + tid + 512] = (bf16)((v2 - mean) * rs * w[tid + 512] + b[tid + 512]);
}

// ---------------- tiled transpose + cast to bf16 ----------------
template <class TI>
__global__ __launch_bounds__(256) void transpose_cast(
    const TI* __restrict__ in, bf16* __restrict__ out,
    int R, int C, long sInB, long sOutB)
{
  __shared__ float tile[64][65];
  const TI* ib = in  + (long)blockIdx.z * sInB;
  bf16*     ob = out + (long)blockIdx.z * sOutB;
  const int c0 = blockIdx.x * 64, r0 = blockIdx.y * 64;
  const int lc = threadIdx.x & 63, lr0 = threadIdx.x >> 6;
#pragma unroll
  for (int i = 0; i < 16; i++) {
    int r = lr0 + i * 4;
    tile[r][lc] = (float)ib[(long)(r0 + r) * C + c0 + lc];
  }
  __syncthreads();
#pragma unroll
  for (int i = 0; i < 16; i++) {
    int r = lr0 + i * 4;
    ob[(long)(c0 + r) * R + r0 + lc] = (bf16)tile[lc][r];
  }
}

// ---------------- RoPE sin/cos table ----------------
__global__ __launch_bounds__(256) void rope_table_kernel(
    const float* __restrict__ invf, float2* __restrict__ tab)
{
  int idx = blockIdx.x * 256 + threadIdx.x;   // 4096*64 entries
  int p = idx >> 6, i = idx & 63;
  float arg = (float)p * invf[i];
  double a = (double)arg;
  tab[idx] = make_float2((float)sin(a), (float)cos(a));
}

// ---------------- z -> gamma/beta -> rope -> 4 gate rows ----------------
__global__ __launch_bounds__(128) void rope_kernel(
    const bf16* __restrict__ zbuf, const float* __restrict__ gamma,
    const float* __restrict__ beta, const float2* __restrict__ tab,
    bf16* __restrict__ qq, bf16* __restrict__ qk,
    bf16* __restrict__ lq, bf16* __restrict__ lk)
{
  const long t = blockIdx.x;
  const int s = threadIdx.x;
  const int p = (int)(t & 4095);
  const int i = s & 63;
  const float2 sc = tab[p * 64 + i];
  const bf16* zr = zbuf + t * S_;
  const float zlo = (float)zr[i], zhi = (float)zr[i + 64];
  bf16* outs[4] = {qq, qk, lq, lk};
#pragma unroll
  for (int r = 0; r < 4; r++) {
    float zl = zlo * gamma[r * 128 + i]      + beta[r * 128 + i];
    float zh = zhi * gamma[r * 128 + i + 64] + beta[r * 128 + i + 64];
    float val = (s < 64) ? (zl * sc.y - zh * sc.x) : (zh * sc.y + zl * sc.x);
    outs[r][t * S_ + s] = (bf16)val;
  }
}

// ---------------- segment mask ----------------
__global__ __launch_bounds__(64) void mask_kernel(const int* __restrict__ seg, float* __restrict__ mask) {
  __shared__ int mn[16], mx[16];
  const int b = blockIdx.x, tid = threadIdx.x;
  if (tid < 16) {
    const int* p = seg + (long)b * 4096 + tid * 256;
    int lo = p[0], hi = p[0];
    for (int i = 1; i < 256; i++) { int v = p[i]; lo = min(lo, v); hi = max(hi, v); }
    mn[tid] = lo; mx[tid] = hi;
  }
  __syncthreads();
  if (tid < 16) {
    const int g = tid;
    float row[16]; float s = 0.f;
    for (int h = 0; h < 16; h++) {
      float o = (mn[g] <= mx[h] && mx[g] >= mn[h]) ? 1.f : 0.f;
      row[h] = o; s += o;
    }
    const float inv = 1.f / s;
    for (int h = 0; h < 16; h++) mask[((long)b * 16 + g) * 16 + h] = row[h] * inv;
  }
}

// ---------------- mask-mix of P2 (folds 1/n) ----------------
__global__ __launch_bounds__(256) void mix_kernel(
    const float* __restrict__ P2, const float* __restrict__ mask, bf16* __restrict__ amix)
{
  const int z = blockIdx.x;          // b*16 + g
  const int b = z >> 4;
  float m[16];
#pragma unroll
  for (int h = 0; h < 16; h++) m[h] = mask[(long)z * 16 + h] * (1.f / 256.f);
  const float* Pb = P2 + (long)b * 16 * 16384;
  bf16* Ab = amix + (long)z * 16384;
#pragma unroll 4
  for (int j = 0; j < 16; j++) {
    int c = j * 256 + threadIdx.x;   // float4 chunk id (4096 per matrix)
    float ax = 0, ay = 0, az = 0, aw = 0;
#pragma unroll
    for (int h = 0; h < 16; h++) {
      float4 p = ((const float4*)(Pb + (long)h * 16384))[c];
      ax += m[h] * p.x; ay += m[h] * p.y; az += m[h] * p.z; aw += m[h] * p.w;
    }
    bf16x4 o; o[0] = (bf16)ax; o[1] = (bf16)ay; o[2] = (bf16)az; o[3] = (bf16)aw;
    *(bf16x4*)&Ab[(long)c * 4] = o;
  }
}

// ---------------- launch ----------------
extern "C" void kernel_launch(void* const* d_in, const int* in_sizes, int n_in,
                              void* d_out, int out_size, void* d_ws, size_t ws_size,
                              hipStream_t stream)
{
  const float* x0    = (const float*)d_in[0];
  const int*   seg   = (const int*)d_in[1];
  const float* lnw   = (const float*)d_in[2];
  const float* lnb   = (const float*)d_in[3];
  const float* W1    = (const float*)d_in[4];
  const float* b1    = (const float*)d_in[5];
  const float* gamma = (const float*)d_in[6];
  const float* beta  = (const float*)d_in[7];
  const float* W2    = (const float*)d_in[8];
  const float* b2    = (const float*)d_in[9];
  const float* wrel  = (const float*)d_in[10];
  float* out = (float*)d_out;
  char* ws = (char*)d_ws;

  bf16*   w1t   = (bf16*)(ws + OFF_W1T);
  bf16*   w2t   = (bf16*)(ws + OFF_W2T);
  float2* tab   = (float2*)(ws + OFF_TAB);
  bf16*   xn    = (bf16*)(ws + OFF_XN);
  bf16*   ker   = (bf16*)(ws + OFF_KER);
  bf16*   qq    = (bf16*)(ws + OFF_QQ);
  bf16*   qk    = (bf16*)(ws + OFF_QK);
  bf16*   lq    = (bf16*)(ws + OFF_LQ);
  bf16*   u     = (bf16*)(ws + OFF_U);
  bf16*   zb    = (bf16*)(ws + OFF_Z);
  float*  P2    = (float*)(ws + OFF_Z);       // reuse (z dead after rope)
  bf16*   lk    = (bf16*)(ws + OFF_LK);
  bf16*   T1    = (bf16*)(ws + OFF_LK);       // reuse (lk dead after lkT)
  bf16*   lqT   = (bf16*)(ws + OFF_LQT);
  bf16*   amix  = (bf16*)(ws + OFF_LQT);      // reuse (lqT dead after P2)
  bf16*   kvT   = (bf16*)(ws + OFF_LQT + 4194304UL);
  bf16*   lkT   = (bf16*)(ws + OFF_LKT);
  float*  maskb = (float*)(ws + OFF_MASK);
  float*  invfd = (float*)(ws + OFF_INVF);
  bf16*   vTd   = (bf16*)d_out;               // vT lives in d_out (exact fit), dead before final GEMM

  // invf on host with the same libm numpy uses (recomputed every call; static storage only)
  static float h_invf[64];
  for (int i = 0; i < 64; i++) h_invf[i] = powf(10000.0f, (float)i * (1.0f / 64.0f));
  hipMemcpyAsync(invfd, h_invf, 64 * sizeof(float), hipMemcpyHostToDevice, stream);

  // prep (independent)
  transpose_cast<float><<<dim3(50, 12, 1), 256, 0, stream>>>(W1, w1t, 768, 3200, 0, 0);
  transpose_cast<float><<<dim3(12, 24, 1), 256, 0, stream>>>(W2, w2t, 1536, 768, 0, 0);
  rope_table_kernel<<<1024, 256, 0, stream>>>(invfd, tab);
  mask_kernel<<<8, 64, 0, stream>>>(seg, maskb);

  // LN -> xn (bf16)
  ln_kernel<<<TT_, 256, 0, stream>>>(x0, lnw, lnb, xn);

  // GEMM1: silu(xn@W1 + b1) -> u, vT(d_out), z
  gemm_bt<EpiGemm1, false><<<dim3(256, 25, 1), 256, 0, stream>>>(
      xn, w1t, 768, 768, 768, 0, 0, 0, 0,
      nullptr, nullptr, 0, 0, 0, 0, 0, 0, 0, 1, EpiGemm1{b1, u, vTd, zb});

  // z -> 4 rope'd gate rows
  rope_kernel<<<TT_, 128, 0, stream>>>(zb, gamma, beta, tab, qq, qk, lq, lk);

  // lq/lk -> transposed (per b: 4096x128 -> 128x4096)
  transpose_cast<bf16><<<dim3(2, 64, 8), 256, 0, stream>>>(lq, lqT, 4096, 128, 524288, 524288);
  transpose_cast<bf16><<<dim3(2, 64, 8), 256, 0, stream>>>(lk, lkT, 4096, 128, 524288, 524288);

  // P2[b,h][s][k] = sum_c lq[c][s] lk[c][k]  (into dead z region)
  gemm_bt<EpiF32, false><<<dim3(1, 1, 128), 256, 0, stream>>>(
      lqT, lkT, 4096, 4096, 256, 524288, 256, 524288, 256,
      nullptr, nullptr, 0, 0, 0, 0, 0, 0, 0, 16, EpiF32{P2, 262144, 16384, 128});

  // amix[b,g] = sum_h mask/n * P2[b,h]  (into dead lqT region)
  mix_kernel<<<128, 256, 0, stream>>>(P2, maskb, amix);

  // kvT[b][e][s] = sum_t v[t][e] lk[t][s]
  gemm_bt<EpiBf16, false><<<dim3(12, 1, 8), 256, 0, stream>>>(
      vTd, lkT, 4096, 4096, 4096, 6291456, 0, 524288, 0,
      nullptr, nullptr, 0, 0, 0, 0, 0, 0, 0, 1, EpiBf16{kvT, 196608, 0, 128});

  // T1[t][s] = sum_k lq[t][k] amix[b,g][s][k]  (into dead lk region)
  gemm_bt<EpiBf16, false><<<dim3(2, 1, 128), 256, 0, stream>>>(
      lq, amix, 128, 128, 128, 32768, 0, 16384, 0,
      nullptr, nullptr, 0, 0, 0, 0, 0, 0, 0, 1, EpiBf16{T1, 32768, 0, 128});

  // ker[b,g][n][m] = relu(qq.qk/n + bias)^2  (into dead xn region)
  gemm_bt<EpiKer, false><<<dim3(2, 2, 128), 256, 0, stream>>>(
      qq, qk, 128, 128, 128, 32768, 0, 32768, 0,
      nullptr, nullptr, 0, 0, 0, 0, 0, 0, 0, 1, EpiKer{ker, wrel});

  // combine (dual-K): P = u * (ker@v + T1@kv), in-place over u
  gemm_bt<EpiCombine, true><<<dim3(2, 12, 128), 256, 0, stream>>>(
      ker, vTd, 256, 4096, 256, 1048576, 65536, 6291456, 256,
      T1, kvT, 128, 128, 128, 524288, 32768, 196608, 0, 16, EpiCombine{u});

  // out = P@W2 + b2 + shortcut (vT in d_out is dead now)
  gemm_bt<EpiFinal, false><<<dim3(256, 6, 1), 256, 0, stream>>>(
      u, w2t, 1536, 1536, 1536, 0, 0, 0, 0,
      nullptr, nullptr, 0, 0, 0, 0, 0, 0, 0, 1, EpiFinal{out, b2, x0});
}